// Round 15
// baseline (449.393 us; speedup 1.0000x reference)
//
#include <hip/hip_runtime.h>
#include <hip/hip_bf16.h>
#include <hip/hip_fp16.h>
#include <math.h>

constexpr int NN = 50000;   // nodes
constexpr int NE = 800000;  // edges (without self loops)
constexpr float L2E = 1.44269504f;  // log2(e)
constexpr int SBLK = 256;
constexpr int SGRID = (NN + SBLK - 1) / SBLK;  // 196
constexpr int NSLICE = 8;                      // XCD count
constexpr int DPS = (NN + NSLICE - 1) / NSLICE;  // 6250 nodes per slice

typedef __attribute__((ext_vector_type(8))) short bf16x8;
typedef __attribute__((ext_vector_type(4))) float f32x4;

__device__ inline float b2f(unsigned short u) {
  union { unsigned int i; float f; } v;
  v.i = ((unsigned int)u) << 16;
  return v.f;
}

// ---------------------------------------------------------------------------
__global__ void k_deg(const int* __restrict__ dst, int* __restrict__ degin) {
  int i = blockIdx.x * blockDim.x + threadIdx.x;
  if (i < NE) atomicAdd(&degin[dst[i]], 1);
}

// ---- hierarchical exclusive scan ----
__global__ void k_scan1(const int* __restrict__ deg, int* __restrict__ bsum) {
  int i = blockIdx.x * SBLK + threadIdx.x;
  int v = (i < NN) ? deg[i] : 0;
#pragma unroll
  for (int off = 32; off; off >>= 1) v += __shfl_down(v, off, 64);
  __shared__ int ws[SBLK / 64];
  if ((threadIdx.x & 63) == 0) ws[threadIdx.x >> 6] = v;
  __syncthreads();
  if (threadIdx.x == 0) {
    int s = 0;
#pragma unroll
    for (int w = 0; w < SBLK / 64; ++w) s += ws[w];
    bsum[blockIdx.x] = s;
  }
}

__global__ void k_scan2(int* __restrict__ bsum) {
  __shared__ int ls[256];
  int t = threadIdx.x;
  int v = (t < SGRID) ? bsum[t] : 0;
  ls[t] = v;
  __syncthreads();
  for (int off = 1; off < 256; off <<= 1) {
    int u = (t >= off) ? ls[t - off] : 0;
    __syncthreads();
    ls[t] += u;
    __syncthreads();
  }
  if (t < SGRID) bsum[t] = ls[t] - v;
}

__global__ void k_scan3(const int* __restrict__ deg, const int* __restrict__ bsum,
                        int* __restrict__ base, int* __restrict__ cursor) {
  __shared__ int ls[SBLK];
  int t = threadIdx.x;
  int i = blockIdx.x * SBLK + t;
  int v = (i < NN) ? deg[i] : 0;
  ls[t] = v;
  __syncthreads();
  for (int off = 1; off < SBLK; off <<= 1) {
    int u = (t >= off) ? ls[t - off] : 0;
    __syncthreads();
    ls[t] += u;
    __syncthreads();
  }
  int ex = ls[t] - v + bsum[blockIdx.x];
  if (i < NN) { base[i] = ex; cursor[i] = ex; }
}

// XCD-sliced scatter: block i%8 handles dst-slice i%8 only (one XCD's L2
// owns each csrc range -> single writeback per line). Edge list re-read 8x.
__global__ void k_scatter(const int* __restrict__ src, const int* __restrict__ dst,
                          int* __restrict__ cursor, int* __restrict__ csrc) {
  const int slice = blockIdx.x & (NSLICE - 1);
  const int chunk = blockIdx.x >> 3;
  const int nchunks = gridDim.x >> 3;
  for (int e = chunk * blockDim.x + threadIdx.x; e < NE;
       e += nchunks * blockDim.x) {
    int d = dst[e];
    if (d / DPS == slice) {
      int pos = atomicAdd(&cursor[d], 1);
      csrc[pos] = src[e];
    }
  }
}

// dstpos[k] = owning node (coalesced fill); lane 0 also writes inv[n].
__global__ void k_dstpos(const int* __restrict__ cscbase, const int* __restrict__ degin,
                         int* __restrict__ dstpos, float* __restrict__ inv) {
  const int lane = threadIdx.x & 63;
  const int n = (int)(((long)blockIdx.x * blockDim.x + threadIdx.x) >> 6);
  if (n >= NN) return;
  const int dg = degin[n];
  if (lane == 0) inv[n] = 1.0f / (float)(dg + 1);
  const int base = cscbase[n];
  const int end = base + dg;
  for (int k = base + lane; k < end; k += 64) dstpos[k] = n;
}

// ---------------------------------------------------------------------------
// build W''[o][h*64+c] = W[h*Cout+o][c] as bf16
__global__ void k_wt(const float* __restrict__ w1, const float* __restrict__ w2,
                     const float* __restrict__ w3, __hip_bfloat16* __restrict__ t1,
                     __hip_bfloat16* __restrict__ t2, __hip_bfloat16* __restrict__ t3) {
  int i = blockIdx.x * blockDim.x + threadIdx.x;
  const int n1 = 64 * 512, n2 = 64 * 512, n3 = 32 * 512;
  const float* w; __hip_bfloat16* t; int cout; int j = i;
  if (j < n1) { w = w1; t = t1; cout = 64; }
  else if ((j -= n1) < n2) { w = w2; t = t2; cout = 64; }
  else if ((j -= n2) < n3) { w = w3; t = t3; cout = 32; }
  else return;
  int o = j >> 9;
  int hc = j & 511;
  int h = hc >> 6, c = hc & 63;
  t[j] = __float2bfloat16(w[(h * cout + o) * 64 + c]);
}

// ---------------------------------------------------------------------------
// layer-1 prep (thread per node): q[n,h] = L2E * x_n . U_h  AND xb = bf16(x_n)
__global__ void k_qx(const float* __restrict__ X, const float* __restrict__ U,
                     float* __restrict__ q, __hip_bfloat16* __restrict__ xb) {
  int n = blockIdx.x * blockDim.x + threadIdx.x;
  if (n >= NN) return;
  float4 xr[16];
  const float4* X4 = reinterpret_cast<const float4*>(X) + (size_t)n * 16;
#pragma unroll
  for (int i = 0; i < 16; ++i) xr[i] = X4[i];

  // bf16 row write (contiguous 128B per thread, wave-coalesced)
  uint4* xo = reinterpret_cast<uint4*>(reinterpret_cast<ushort*>(xb) + (size_t)n * 64);
#pragma unroll
  for (int i = 0; i < 8; ++i) {
    float4 va = xr[2 * i], vb = xr[2 * i + 1];
    ushort u0 = __hip_bfloat16_raw(__float2bfloat16(va.x)).x;
    ushort u1 = __hip_bfloat16_raw(__float2bfloat16(va.y)).x;
    ushort u2 = __hip_bfloat16_raw(__float2bfloat16(va.z)).x;
    ushort u3 = __hip_bfloat16_raw(__float2bfloat16(va.w)).x;
    ushort u4 = __hip_bfloat16_raw(__float2bfloat16(vb.x)).x;
    ushort u5 = __hip_bfloat16_raw(__float2bfloat16(vb.y)).x;
    ushort u6 = __hip_bfloat16_raw(__float2bfloat16(vb.z)).x;
    ushort u7 = __hip_bfloat16_raw(__float2bfloat16(vb.w)).x;
    uint4 o;
    o.x = (unsigned)u0 | ((unsigned)u1 << 16);
    o.y = (unsigned)u2 | ((unsigned)u3 << 16);
    o.z = (unsigned)u4 | ((unsigned)u5 << 16);
    o.w = (unsigned)u6 | ((unsigned)u7 << 16);
    xo[i] = o;
  }

  const float4* U4 = reinterpret_cast<const float4*>(U);
#pragma unroll
  for (int h = 0; h < 8; ++h) {
    float a = 0.f;
#pragma unroll
    for (int i = 0; i < 16; ++i) {
      float4 u = U4[h * 16 + i];
      a = fmaf(xr[i].x, u.x, a);
      a = fmaf(xr[i].y, u.y, a);
      a = fmaf(xr[i].z, u.z, a);
      a = fmaf(xr[i].w, u.w, a);
    }
    q[(size_t)n * 8 + h] = a * L2E;
  }
}

// ---------------------------------------------------------------------------
// lane = CSC position: a[k] = 8 x f16 of exp(l_h)/sum * inv_count[dst].
__global__ void k_attn(const int* __restrict__ csrc, const int* __restrict__ dstpos,
                       const float* __restrict__ q, const float* __restrict__ cvec,
                       const float* __restrict__ inv, uint4* __restrict__ a) {
  int k = blockIdx.x * blockDim.x + threadIdx.x;
  if (k >= NE) return;
  int s = csrc[k], d = dstpos[k];

  const float4* q4 = reinterpret_cast<const float4*>(q);
  const float4* c4 = reinterpret_cast<const float4*>(cvec);
  float4 qd0 = q4[2 * d], qd1 = q4[2 * d + 1];
  float4 qs0 = q4[2 * s], qs1 = q4[2 * s + 1];
  float4 c0 = c4[0], c1 = c4[1];

  float e[8];
  e[0] = __builtin_amdgcn_exp2f(qd0.x - qs0.x + c0.x * L2E);
  e[1] = __builtin_amdgcn_exp2f(qd0.y - qs0.y + c0.y * L2E);
  e[2] = __builtin_amdgcn_exp2f(qd0.z - qs0.z + c0.z * L2E);
  e[3] = __builtin_amdgcn_exp2f(qd0.w - qs0.w + c0.w * L2E);
  e[4] = __builtin_amdgcn_exp2f(qd1.x - qs1.x + c1.x * L2E);
  e[5] = __builtin_amdgcn_exp2f(qd1.y - qs1.y + c1.y * L2E);
  e[6] = __builtin_amdgcn_exp2f(qd1.z - qs1.z + c1.z * L2E);
  e[7] = __builtin_amdgcn_exp2f(qd1.w - qs1.w + c1.w * L2E);

  float sum = ((e[0] + e[1]) + (e[2] + e[3])) + ((e[4] + e[5]) + (e[6] + e[7]));
  float r = __builtin_amdgcn_rcpf(sum) * inv[d];

  __half2 h0 = __floats2half2_rn(e[0] * r, e[1] * r);
  __half2 h1 = __floats2half2_rn(e[2] * r, e[3] * r);
  __half2 h2 = __floats2half2_rn(e[4] * r, e[5] * r);
  __half2 h3 = __floats2half2_rn(e[6] * r, e[7] * r);
  uint4 o;
  o.x = *(unsigned int*)&h0;
  o.y = *(unsigned int*)&h1;
  o.z = *(unsigned int*)&h2;
  o.w = *(unsigned int*)&h3;
  a[k] = o;
}

// ---------------------------------------------------------------------------
// z-aggregation (dst-major, NO atomics): wave = dst node, lane = input channel.
// Edge loop unrolled x8 (then x4, then x1): 8 x-gathers in flight per wave.
#define ZACC(AV, XS)                                                      \
  do {                                                                    \
    float2 f0 = __half22float2(*(__half2*)&(AV).x);                       \
    float2 f1 = __half22float2(*(__half2*)&(AV).y);                       \
    float2 f2 = __half22float2(*(__half2*)&(AV).z);                       \
    float2 f3 = __half22float2(*(__half2*)&(AV).w);                       \
    z[0] = fmaf(f0.x, (XS), z[0]);                                        \
    z[1] = fmaf(f0.y, (XS), z[1]);                                        \
    z[2] = fmaf(f1.x, (XS), z[2]);                                        \
    z[3] = fmaf(f1.y, (XS), z[3]);                                        \
    z[4] = fmaf(f2.x, (XS), z[4]);                                        \
    z[5] = fmaf(f2.y, (XS), z[5]);                                        \
    z[6] = fmaf(f3.x, (XS), z[6]);                                        \
    z[7] = fmaf(f3.y, (XS), z[7]);                                        \
  } while (0)

__global__ void k_zagg(const int* __restrict__ cscbase, const int* __restrict__ cscend,
                       const int* __restrict__ csrc, const uint4* __restrict__ a,
                       const ushort* __restrict__ xb, const float* __restrict__ inv,
                       const float* __restrict__ cvec, __hip_bfloat16* __restrict__ zb) {
  const int lane = threadIdx.x & 63;
  const int n = (int)(((long)blockIdx.x * blockDim.x + threadIdx.x) >> 6);
  if (n >= NN) return;

  // self-loop init: z[h] = softmax(c)[h] * inv[n] * x_n[lane]
  float wc[8], wsum = 0.f;
#pragma unroll
  for (int h = 0; h < 8; ++h) { wc[h] = __builtin_amdgcn_exp2f(cvec[h] * L2E); wsum += wc[h]; }
  const float rxd = __builtin_amdgcn_rcpf(wsum) * inv[n] * b2f(xb[(size_t)n * 64 + lane]);
  float z[8];
#pragma unroll
  for (int h = 0; h < 8; ++h) z[h] = wc[h] * rxd;

  int k = cscbase[n];
  const int k1 = cscend[n];
  for (; k + 8 <= k1; k += 8) {
    int s[8];
#pragma unroll
    for (int t = 0; t < 8; ++t) s[t] = csrc[k + t];
    uint4 av[8];
#pragma unroll
    for (int t = 0; t < 8; ++t) av[t] = a[k + t];
    float xv[8];
#pragma unroll
    for (int t = 0; t < 8; ++t) xv[t] = b2f(xb[(size_t)s[t] * 64 + lane]);
#pragma unroll
    for (int t = 0; t < 8; ++t) ZACC(av[t], xv[t]);
  }
  for (; k + 4 <= k1; k += 4) {
    int s0 = csrc[k + 0], s1 = csrc[k + 1], s2 = csrc[k + 2], s3 = csrc[k + 3];
    uint4 a0 = a[k + 0], a1 = a[k + 1], a2 = a[k + 2], a3 = a[k + 3];
    float x0 = b2f(xb[(size_t)s0 * 64 + lane]);
    float x1 = b2f(xb[(size_t)s1 * 64 + lane]);
    float x2 = b2f(xb[(size_t)s2 * 64 + lane]);
    float x3 = b2f(xb[(size_t)s3 * 64 + lane]);
    ZACC(a0, x0);
    ZACC(a1, x1);
    ZACC(a2, x2);
    ZACC(a3, x3);
  }
  for (; k < k1; ++k) {
    int s = csrc[k];
    uint4 av = a[k];
    float xs = b2f(xb[(size_t)s * 64 + lane]);
    ZACC(av, xs);
  }

  ushort* zo = reinterpret_cast<ushort*>(zb) + (size_t)n * 512 + lane;
#pragma unroll
  for (int h = 0; h < 8; ++h)
    zo[h * 64] = __hip_bfloat16_raw(__float2bfloat16(z[h])).x;
}

// ---------------------------------------------------------------------------
// GEMM + epilogue. RS=true: yb = bf16(relu(acc+b)) + BN stats. RS=false: fout = acc+b.
template <int JOUT, bool RS>
__global__ void __launch_bounds__(256)
k_zgemm_ep(const __hip_bfloat16* __restrict__ Zb, const __hip_bfloat16* __restrict__ Wt,
           const float* __restrict__ b, __hip_bfloat16* __restrict__ yb,
           float* __restrict__ fout, float* __restrict__ stats) {
  __shared__ float ssum[64], ssq[64];
  const int lane = threadIdx.x & 63;
  const int w = threadIdx.x >> 6;
  const int m0 = (blockIdx.x * 4 + w) * 64;
  const int lr = lane & 15;
  const int lk = lane >> 4;
  constexpr int NT = JOUT / 16;

  if (RS && threadIdx.x < 64) { ssum[threadIdx.x] = 0.f; ssq[threadIdx.x] = 0.f; }
  if (RS) __syncthreads();

  const ushort* Z = reinterpret_cast<const ushort*>(Zb);
  const ushort* W = reinterpret_cast<const ushort*>(Wt);

  f32x4 acc[4][NT] = {};
  for (int kk = 0; kk < 16; ++kk) {
    bf16x8 bfr[NT];
#pragma unroll
    for (int ni = 0; ni < NT; ++ni) {
      int j = ni * 16 + lr;
      bfr[ni] = *reinterpret_cast<const bf16x8*>(W + (size_t)j * 512 + kk * 32 + lk * 8);
    }
#pragma unroll
    for (int mi = 0; mi < 4; ++mi) {
      int r = m0 + mi * 16 + lr;
      if (r >= NN) r = NN - 1;
      bf16x8 afr = *reinterpret_cast<const bf16x8*>(Z + (size_t)r * 512 + kk * 32 + lk * 8);
#pragma unroll
      for (int ni = 0; ni < NT; ++ni)
        acc[mi][ni] = __builtin_amdgcn_mfma_f32_16x16x32_bf16(afr, bfr[ni], acc[mi][ni], 0, 0, 0);
    }
  }

  float bj[NT];
#pragma unroll
  for (int ni = 0; ni < NT; ++ni) bj[ni] = b[ni * 16 + lr];

  float ps[NT] = {}, pq[NT] = {};
#pragma unroll
  for (int mi = 0; mi < 4; ++mi) {
#pragma unroll
    for (int i = 0; i < 4; ++i) {
      int r = m0 + mi * 16 + lk * 4 + i;
      if (r < NN) {
#pragma unroll
        for (int ni = 0; ni < NT; ++ni) {
          float v = acc[mi][ni][i] + bj[ni];
          if (RS) {
            v = fmaxf(v, 0.f);
            ps[ni] += v;
            pq[ni] = fmaf(v, v, pq[ni]);
            yb[(size_t)r * JOUT + ni * 16 + lr] = __float2bfloat16(v);
          } else {
            fout[(size_t)r * JOUT + ni * 16 + lr] = v;
          }
        }
      }
    }
  }

  if (RS) {
#pragma unroll
    for (int ni = 0; ni < NT; ++ni) {
      atomicAdd(&ssum[ni * 16 + lr], ps[ni]);
      atomicAdd(&ssq[ni * 16 + lr], pq[ni]);
    }
    __syncthreads();
    if (threadIdx.x < 64) {
      atomicAdd(&stats[threadIdx.x], ssum[threadIdx.x]);
      atomicAdd(&stats[64 + threadIdx.x], ssq[threadIdx.x]);
    }
  }
}

// ---------------------------------------------------------------------------
// BN + next-layer q, wave per node: lane o normalizes channel o (from bf16 y),
// writes bf16 xb; q[n][h] via 8 shfl_xor butterflies.
__global__ void __launch_bounds__(256)
k_bnq(const __hip_bfloat16* __restrict__ y, const float* __restrict__ stats,
      const float* __restrict__ g, const float* __restrict__ be,
      const float* __restrict__ U, __hip_bfloat16* __restrict__ xb,
      float* __restrict__ q) {
  const int lane = threadIdx.x & 63;
  const int n = (int)(((long)blockIdx.x * blockDim.x + threadIdx.x) >> 6);
  if (n >= NN) return;

  float m = stats[lane] * (1.0f / NN);
  float v = stats[64 + lane] * (1.0f / NN) - m * m;
  float yv = b2f(reinterpret_cast<const ushort*>(y)[(size_t)n * 64 + lane]);
  float r = fmaf(g[lane] * rsqrtf(v + 1e-5f), yv - m, be[lane]);
  xb[(size_t)n * 64 + lane] = __float2bfloat16(r);

  float qv[8];
#pragma unroll
  for (int h = 0; h < 8; ++h) {
    float p = r * U[h * 64 + lane];
#pragma unroll
    for (int off = 32; off; off >>= 1) p += __shfl_xor(p, off, 64);
    qv[h] = p;
  }
  if (lane == 0) {
    float4* q4 = reinterpret_cast<float4*>(q + (size_t)n * 8);
    q4[0] = make_float4(qv[0] * L2E, qv[1] * L2E, qv[2] * L2E, qv[3] * L2E);
    q4[1] = make_float4(qv[4] * L2E, qv[5] * L2E, qv[6] * L2E, qv[7] * L2E);
  }
}

// ---------------------------------------------------------------------------
extern "C" void kernel_launch(void* const* d_in, const int* in_sizes, int n_in,
                              void* d_out, int out_size, void* d_ws, size_t ws_size,
                              hipStream_t stream) {
  const float* x   = (const float*)d_in[0];
  const int*   src = (const int*)d_in[1];
  const int*   dst = src + NE;
  const float* W1 = (const float*)d_in[2];
  const float* U1 = (const float*)d_in[3];
  const float* c1 = (const float*)d_in[4];
  const float* b1 = (const float*)d_in[5];
  const float* g1 = (const float*)d_in[6];
  const float* be1 = (const float*)d_in[7];
  const float* W2 = (const float*)d_in[8];
  const float* U2 = (const float*)d_in[9];
  const float* c2 = (const float*)d_in[10];
  const float* b2 = (const float*)d_in[11];
  const float* g2 = (const float*)d_in[12];
  const float* be2 = (const float*)d_in[13];
  const float* W3 = (const float*)d_in[14];
  const float* U3 = (const float*)d_in[15];
  const float* c3 = (const float*)d_in[16];
  const float* b3 = (const float*)d_in[17];
  float* out = (float*)d_out;

  // workspace layout (all sections 16B-aligned)
  float* ws   = (float*)d_ws;
  float* inv  = ws;                           // N
  float* q    = inv + NN;                     // N*8
  float* stats = q + (size_t)NN * 8;          // 256 (two layers' stats)
  uint4* a    = (uint4*)(stats + 256);        // NE (f16x8 attn weights)
  __hip_bfloat16* yb = (__hip_bfloat16*)(a + NE);        // N*64 bf16 (relu out)
  __hip_bfloat16* xb = yb + (size_t)NN * 64;             // N*64 bf16
  __hip_bfloat16* zb = xb + (size_t)NN * 64;             // N*512 bf16
  __hip_bfloat16* Wt1 = zb + (size_t)NN * 512;           // 64*512 bf16
  __hip_bfloat16* Wt2 = Wt1 + 64 * 512;
  __hip_bfloat16* Wt3 = Wt2 + 64 * 512;
  int* degin   = (int*)(Wt3 + 32 * 512);            // N
  int* cscbase = degin + NN;                        // N
  int* cursor  = cscbase + NN;                      // N (CSC end after scatter)
  int* bsum    = cursor + NN;                       // 256
  int* csrc    = bsum + 256;                        // NE
  int* dstpos  = csrc + NE;                         // NE
  float* stats1 = stats;
  float* stats2 = stats + 128;

  const int BLK = 256;
  dim3 b256(BLK);

  // ---- CSC build (once; reused by all 3 layers) ----
  hipMemsetAsync(degin, 0, (size_t)NN * 4, stream);
  hipMemsetAsync(stats, 0, 256 * 4, stream);
  k_deg<<<dim3((NE + BLK - 1) / BLK), b256, 0, stream>>>(dst, degin);
  k_scan1<<<dim3(SGRID), dim3(SBLK), 0, stream>>>(degin, bsum);
  k_scan2<<<dim3(1), dim3(256), 0, stream>>>(bsum);
  k_scan3<<<dim3(SGRID), dim3(SBLK), 0, stream>>>(degin, bsum, cscbase, cursor);
  k_scatter<<<dim3(8 * 104), b256, 0, stream>>>(src, dst, cursor, csrc);
  k_dstpos<<<dim3(NN * 64 / BLK), b256, 0, stream>>>(cscbase, degin, dstpos, inv);

  const int qgrid = (NN + BLK - 1) / BLK;
  const int attn_grid = (NE + BLK - 1) / BLK;
  const int node_grid = NN * 64 / BLK;             // 12500 (wave per node)
  const int zgemm_grid = (NN + 255) / 256;         // 196
  const int wtgrid = (64 * 512 * 2 + 32 * 512 + BLK - 1) / BLK;

  k_wt<<<dim3(wtgrid), b256, 0, stream>>>(W1, W2, W3, Wt1, Wt2, Wt3);
  k_qx<<<dim3(qgrid), b256, 0, stream>>>(x, U1, q, xb);

  // ---- layer 1 ----
  k_attn<<<dim3(attn_grid), b256, 0, stream>>>(csrc, dstpos, q, c1, inv, a);
  k_zagg<<<dim3(node_grid), b256, 0, stream>>>(cscbase, cursor, csrc, a,
                                               (const ushort*)xb, inv, c1, zb);
  k_zgemm_ep<64, true><<<dim3(zgemm_grid), b256, 0, stream>>>(zb, Wt1, b1, yb, nullptr, stats1);
  k_bnq<<<dim3(node_grid), b256, 0, stream>>>(yb, stats1, g1, be1, U2, xb, q);

  // ---- layer 2 ----
  k_attn<<<dim3(attn_grid), b256, 0, stream>>>(csrc, dstpos, q, c2, inv, a);
  k_zagg<<<dim3(node_grid), b256, 0, stream>>>(cscbase, cursor, csrc, a,
                                               (const ushort*)xb, inv, c2, zb);
  k_zgemm_ep<64, true><<<dim3(zgemm_grid), b256, 0, stream>>>(zb, Wt2, b2, yb, nullptr, stats2);
  k_bnq<<<dim3(node_grid), b256, 0, stream>>>(yb, stats2, g2, be2, U3, xb, q);

  // ---- layer 3 ----
  k_attn<<<dim3(attn_grid), b256, 0, stream>>>(csrc, dstpos, q, c3, inv, a);
  k_zagg<<<dim3(node_grid), b256, 0, stream>>>(cscbase, cursor, csrc, a,
                                               (const ushort*)xb, inv, c3, zb);
  k_zgemm_ep<32, false><<<dim3(zgemm_grid), b256, 0, stream>>>(zb, Wt3, b3, nullptr, out, nullptr);
}

// Round 16
// 408.902 us; speedup vs baseline: 1.0990x; 1.0990x over previous
//
#include <hip/hip_runtime.h>
#include <hip/hip_bf16.h>
#include <hip/hip_fp16.h>
#include <math.h>

constexpr int NN = 50000;   // nodes
constexpr int NE = 800000;  // edges (without self loops)
constexpr float L2E = 1.44269504f;  // log2(e)
constexpr int SBLK = 256;
constexpr int SGRID = (NN + SBLK - 1) / SBLK;  // 196
constexpr int NSLICE = 8;                      // XCD count
constexpr int DPS = (NN + NSLICE - 1) / NSLICE;  // 6250 nodes per slice

typedef __attribute__((ext_vector_type(8))) short bf16x8;
typedef __attribute__((ext_vector_type(4))) float f32x4;

__device__ inline float b2f(unsigned short u) {
  union { unsigned int i; float f; } v;
  v.i = ((unsigned int)u) << 16;
  return v.f;
}

// ---------------------------------------------------------------------------
__global__ void k_deg(const int* __restrict__ dst, int* __restrict__ degin) {
  int i = blockIdx.x * blockDim.x + threadIdx.x;
  if (i < NE) atomicAdd(&degin[dst[i]], 1);
}

// ---- hierarchical exclusive scan ----
__global__ void k_scan1(const int* __restrict__ deg, int* __restrict__ bsum) {
  int i = blockIdx.x * SBLK + threadIdx.x;
  int v = (i < NN) ? deg[i] : 0;
#pragma unroll
  for (int off = 32; off; off >>= 1) v += __shfl_down(v, off, 64);
  __shared__ int ws[SBLK / 64];
  if ((threadIdx.x & 63) == 0) ws[threadIdx.x >> 6] = v;
  __syncthreads();
  if (threadIdx.x == 0) {
    int s = 0;
#pragma unroll
    for (int w = 0; w < SBLK / 64; ++w) s += ws[w];
    bsum[blockIdx.x] = s;
  }
}

__global__ void k_scan2(int* __restrict__ bsum) {
  __shared__ int ls[256];
  int t = threadIdx.x;
  int v = (t < SGRID) ? bsum[t] : 0;
  ls[t] = v;
  __syncthreads();
  for (int off = 1; off < 256; off <<= 1) {
    int u = (t >= off) ? ls[t - off] : 0;
    __syncthreads();
    ls[t] += u;
    __syncthreads();
  }
  if (t < SGRID) bsum[t] = ls[t] - v;
}

__global__ void k_scan3(const int* __restrict__ deg, const int* __restrict__ bsum,
                        int* __restrict__ base, int* __restrict__ cursor) {
  __shared__ int ls[SBLK];
  int t = threadIdx.x;
  int i = blockIdx.x * SBLK + t;
  int v = (i < NN) ? deg[i] : 0;
  ls[t] = v;
  __syncthreads();
  for (int off = 1; off < SBLK; off <<= 1) {
    int u = (t >= off) ? ls[t - off] : 0;
    __syncthreads();
    ls[t] += u;
    __syncthreads();
  }
  int ex = ls[t] - v + bsum[blockIdx.x];
  if (i < NN) { base[i] = ex; cursor[i] = ex; }
}

// XCD-sliced scatter: block i%8 handles dst-slice i%8 only (one XCD's L2
// owns each csrc range -> single writeback per line). Edge list re-read 8x.
__global__ void k_scatter(const int* __restrict__ src, const int* __restrict__ dst,
                          int* __restrict__ cursor, int* __restrict__ csrc) {
  const int slice = blockIdx.x & (NSLICE - 1);
  const int chunk = blockIdx.x >> 3;
  const int nchunks = gridDim.x >> 3;
  for (int e = chunk * blockDim.x + threadIdx.x; e < NE;
       e += nchunks * blockDim.x) {
    int d = dst[e];
    if (d / DPS == slice) {
      int pos = atomicAdd(&cursor[d], 1);
      csrc[pos] = src[e];
    }
  }
}

// dstpos[k] = owning node (coalesced fill); lane 0 also writes inv[n].
__global__ void k_dstpos(const int* __restrict__ cscbase, const int* __restrict__ degin,
                         int* __restrict__ dstpos, float* __restrict__ inv) {
  const int lane = threadIdx.x & 63;
  const int n = (int)(((long)blockIdx.x * blockDim.x + threadIdx.x) >> 6);
  if (n >= NN) return;
  const int dg = degin[n];
  if (lane == 0) inv[n] = 1.0f / (float)(dg + 1);
  const int base = cscbase[n];
  const int end = base + dg;
  for (int k = base + lane; k < end; k += 64) dstpos[k] = n;
}

// ---------------------------------------------------------------------------
// build W''[o][h*64+c] = W[h*Cout+o][c] as bf16
__global__ void k_wt(const float* __restrict__ w1, const float* __restrict__ w2,
                     const float* __restrict__ w3, __hip_bfloat16* __restrict__ t1,
                     __hip_bfloat16* __restrict__ t2, __hip_bfloat16* __restrict__ t3) {
  int i = blockIdx.x * blockDim.x + threadIdx.x;
  const int n1 = 64 * 512, n2 = 64 * 512, n3 = 32 * 512;
  const float* w; __hip_bfloat16* t; int cout; int j = i;
  if (j < n1) { w = w1; t = t1; cout = 64; }
  else if ((j -= n1) < n2) { w = w2; t = t2; cout = 64; }
  else if ((j -= n2) < n3) { w = w3; t = t3; cout = 32; }
  else return;
  int o = j >> 9;
  int hc = j & 511;
  int h = hc >> 6, c = hc & 63;
  t[j] = __float2bfloat16(w[(h * cout + o) * 64 + c]);
}

// ---------------------------------------------------------------------------
// layer-1 prep (thread per node): q[n,h] = L2E * x_n . U_h  AND xb = bf16(x_n)
__global__ void k_qx(const float* __restrict__ X, const float* __restrict__ U,
                     float* __restrict__ q, __hip_bfloat16* __restrict__ xb) {
  int n = blockIdx.x * blockDim.x + threadIdx.x;
  if (n >= NN) return;
  float4 xr[16];
  const float4* X4 = reinterpret_cast<const float4*>(X) + (size_t)n * 16;
#pragma unroll
  for (int i = 0; i < 16; ++i) xr[i] = X4[i];

  uint4* xo = reinterpret_cast<uint4*>(reinterpret_cast<ushort*>(xb) + (size_t)n * 64);
#pragma unroll
  for (int i = 0; i < 8; ++i) {
    float4 va = xr[2 * i], vb = xr[2 * i + 1];
    ushort u0 = __hip_bfloat16_raw(__float2bfloat16(va.x)).x;
    ushort u1 = __hip_bfloat16_raw(__float2bfloat16(va.y)).x;
    ushort u2 = __hip_bfloat16_raw(__float2bfloat16(va.z)).x;
    ushort u3 = __hip_bfloat16_raw(__float2bfloat16(va.w)).x;
    ushort u4 = __hip_bfloat16_raw(__float2bfloat16(vb.x)).x;
    ushort u5 = __hip_bfloat16_raw(__float2bfloat16(vb.y)).x;
    ushort u6 = __hip_bfloat16_raw(__float2bfloat16(vb.z)).x;
    ushort u7 = __hip_bfloat16_raw(__float2bfloat16(vb.w)).x;
    uint4 o;
    o.x = (unsigned)u0 | ((unsigned)u1 << 16);
    o.y = (unsigned)u2 | ((unsigned)u3 << 16);
    o.z = (unsigned)u4 | ((unsigned)u5 << 16);
    o.w = (unsigned)u6 | ((unsigned)u7 << 16);
    xo[i] = o;
  }

  const float4* U4 = reinterpret_cast<const float4*>(U);
#pragma unroll
  for (int h = 0; h < 8; ++h) {
    float a = 0.f;
#pragma unroll
    for (int i = 0; i < 16; ++i) {
      float4 u = U4[h * 16 + i];
      a = fmaf(xr[i].x, u.x, a);
      a = fmaf(xr[i].y, u.y, a);
      a = fmaf(xr[i].z, u.z, a);
      a = fmaf(xr[i].w, u.w, a);
    }
    q[(size_t)n * 8 + h] = a * L2E;
  }
}

// ---------------------------------------------------------------------------
// lane = CSC position: a[k] = 8 x f16 of exp(l_h)/sum * inv_count[dst].
__global__ void k_attn(const int* __restrict__ csrc, const int* __restrict__ dstpos,
                       const float* __restrict__ q, const float* __restrict__ cvec,
                       const float* __restrict__ inv, uint4* __restrict__ a) {
  int k = blockIdx.x * blockDim.x + threadIdx.x;
  if (k >= NE) return;
  int s = csrc[k], d = dstpos[k];

  const float4* q4 = reinterpret_cast<const float4*>(q);
  const float4* c4 = reinterpret_cast<const float4*>(cvec);
  float4 qd0 = q4[2 * d], qd1 = q4[2 * d + 1];
  float4 qs0 = q4[2 * s], qs1 = q4[2 * s + 1];
  float4 c0 = c4[0], c1 = c4[1];

  float e[8];
  e[0] = __builtin_amdgcn_exp2f(qd0.x - qs0.x + c0.x * L2E);
  e[1] = __builtin_amdgcn_exp2f(qd0.y - qs0.y + c0.y * L2E);
  e[2] = __builtin_amdgcn_exp2f(qd0.z - qs0.z + c0.z * L2E);
  e[3] = __builtin_amdgcn_exp2f(qd0.w - qs0.w + c0.w * L2E);
  e[4] = __builtin_amdgcn_exp2f(qd1.x - qs1.x + c1.x * L2E);
  e[5] = __builtin_amdgcn_exp2f(qd1.y - qs1.y + c1.y * L2E);
  e[6] = __builtin_amdgcn_exp2f(qd1.z - qs1.z + c1.z * L2E);
  e[7] = __builtin_amdgcn_exp2f(qd1.w - qs1.w + c1.w * L2E);

  float sum = ((e[0] + e[1]) + (e[2] + e[3])) + ((e[4] + e[5]) + (e[6] + e[7]));
  float r = __builtin_amdgcn_rcpf(sum) * inv[d];

  __half2 h0 = __floats2half2_rn(e[0] * r, e[1] * r);
  __half2 h1 = __floats2half2_rn(e[2] * r, e[3] * r);
  __half2 h2 = __floats2half2_rn(e[4] * r, e[5] * r);
  __half2 h3 = __floats2half2_rn(e[6] * r, e[7] * r);
  uint4 o;
  o.x = *(unsigned int*)&h0;
  o.y = *(unsigned int*)&h1;
  o.z = *(unsigned int*)&h2;
  o.w = *(unsigned int*)&h3;
  a[k] = o;
}

// ---------------------------------------------------------------------------
// z-aggregation (dst-major, NO atomics): wave = dst node, lane = input channel.
// Edge loop unrolled x4 (VGPR 32, ~62% occupancy — measured optimum; x8
// spills occupancy to 34% and regresses, round 15).
#define ZACC(AV, XS)                                                      \
  do {                                                                    \
    float2 f0 = __half22float2(*(__half2*)&(AV).x);                       \
    float2 f1 = __half22float2(*(__half2*)&(AV).y);                       \
    float2 f2 = __half22float2(*(__half2*)&(AV).z);                       \
    float2 f3 = __half22float2(*(__half2*)&(AV).w);                       \
    z[0] = fmaf(f0.x, (XS), z[0]);                                        \
    z[1] = fmaf(f0.y, (XS), z[1]);                                        \
    z[2] = fmaf(f1.x, (XS), z[2]);                                        \
    z[3] = fmaf(f1.y, (XS), z[3]);                                        \
    z[4] = fmaf(f2.x, (XS), z[4]);                                        \
    z[5] = fmaf(f2.y, (XS), z[5]);                                        \
    z[6] = fmaf(f3.x, (XS), z[6]);                                        \
    z[7] = fmaf(f3.y, (XS), z[7]);                                        \
  } while (0)

__global__ void k_zagg(const int* __restrict__ cscbase, const int* __restrict__ cscend,
                       const int* __restrict__ csrc, const uint4* __restrict__ a,
                       const ushort* __restrict__ xb, const float* __restrict__ inv,
                       const float* __restrict__ cvec, __hip_bfloat16* __restrict__ zb) {
  const int lane = threadIdx.x & 63;
  const int n = (int)(((long)blockIdx.x * blockDim.x + threadIdx.x) >> 6);
  if (n >= NN) return;

  // self-loop init: z[h] = softmax(c)[h] * inv[n] * x_n[lane]
  float wc[8], wsum = 0.f;
#pragma unroll
  for (int h = 0; h < 8; ++h) { wc[h] = __builtin_amdgcn_exp2f(cvec[h] * L2E); wsum += wc[h]; }
  const float rxd = __builtin_amdgcn_rcpf(wsum) * inv[n] * b2f(xb[(size_t)n * 64 + lane]);
  float z[8];
#pragma unroll
  for (int h = 0; h < 8; ++h) z[h] = wc[h] * rxd;

  int k = cscbase[n];
  const int k1 = cscend[n];
  for (; k + 4 <= k1; k += 4) {
    int s0 = csrc[k + 0];
    int s1 = csrc[k + 1];
    int s2 = csrc[k + 2];
    int s3 = csrc[k + 3];
    uint4 a0 = a[k + 0];
    uint4 a1 = a[k + 1];
    uint4 a2 = a[k + 2];
    uint4 a3 = a[k + 3];
    float x0 = b2f(xb[(size_t)s0 * 64 + lane]);
    float x1 = b2f(xb[(size_t)s1 * 64 + lane]);
    float x2 = b2f(xb[(size_t)s2 * 64 + lane]);
    float x3 = b2f(xb[(size_t)s3 * 64 + lane]);
    ZACC(a0, x0);
    ZACC(a1, x1);
    ZACC(a2, x2);
    ZACC(a3, x3);
  }
  for (; k < k1; ++k) {
    int s = csrc[k];
    uint4 av = a[k];
    float xs = b2f(xb[(size_t)s * 64 + lane]);
    ZACC(av, xs);
  }

  ushort* zo = reinterpret_cast<ushort*>(zb) + (size_t)n * 512 + lane;
#pragma unroll
  for (int h = 0; h < 8; ++h)
    zo[h * 64] = __hip_bfloat16_raw(__float2bfloat16(z[h])).x;
}

// ---------------------------------------------------------------------------
// GEMM + epilogue. RS=true: yb = bf16(relu(acc+b)) + BN stats. RS=false: fout = acc+b.
template <int JOUT, bool RS>
__global__ void __launch_bounds__(256)
k_zgemm_ep(const __hip_bfloat16* __restrict__ Zb, const __hip_bfloat16* __restrict__ Wt,
           const float* __restrict__ b, __hip_bfloat16* __restrict__ yb,
           float* __restrict__ fout, float* __restrict__ stats) {
  __shared__ float ssum[64], ssq[64];
  const int lane = threadIdx.x & 63;
  const int w = threadIdx.x >> 6;
  const int m0 = (blockIdx.x * 4 + w) * 64;
  const int lr = lane & 15;
  const int lk = lane >> 4;
  constexpr int NT = JOUT / 16;

  if (RS && threadIdx.x < 64) { ssum[threadIdx.x] = 0.f; ssq[threadIdx.x] = 0.f; }
  if (RS) __syncthreads();

  const ushort* Z = reinterpret_cast<const ushort*>(Zb);
  const ushort* W = reinterpret_cast<const ushort*>(Wt);

  f32x4 acc[4][NT] = {};
  for (int kk = 0; kk < 16; ++kk) {
    bf16x8 bfr[NT];
#pragma unroll
    for (int ni = 0; ni < NT; ++ni) {
      int j = ni * 16 + lr;
      bfr[ni] = *reinterpret_cast<const bf16x8*>(W + (size_t)j * 512 + kk * 32 + lk * 8);
    }
#pragma unroll
    for (int mi = 0; mi < 4; ++mi) {
      int r = m0 + mi * 16 + lr;
      if (r >= NN) r = NN - 1;
      bf16x8 afr = *reinterpret_cast<const bf16x8*>(Z + (size_t)r * 512 + kk * 32 + lk * 8);
#pragma unroll
      for (int ni = 0; ni < NT; ++ni)
        acc[mi][ni] = __builtin_amdgcn_mfma_f32_16x16x32_bf16(afr, bfr[ni], acc[mi][ni], 0, 0, 0);
    }
  }

  float bj[NT];
#pragma unroll
  for (int ni = 0; ni < NT; ++ni) bj[ni] = b[ni * 16 + lr];

  float ps[NT] = {}, pq[NT] = {};
#pragma unroll
  for (int mi = 0; mi < 4; ++mi) {
#pragma unroll
    for (int i = 0; i < 4; ++i) {
      int r = m0 + mi * 16 + lk * 4 + i;
      if (r < NN) {
#pragma unroll
        for (int ni = 0; ni < NT; ++ni) {
          float v = acc[mi][ni][i] + bj[ni];
          if (RS) {
            v = fmaxf(v, 0.f);
            ps[ni] += v;
            pq[ni] = fmaf(v, v, pq[ni]);
            yb[(size_t)r * JOUT + ni * 16 + lr] = __float2bfloat16(v);
          } else {
            fout[(size_t)r * JOUT + ni * 16 + lr] = v;
          }
        }
      }
    }
  }

  if (RS) {
#pragma unroll
    for (int ni = 0; ni < NT; ++ni) {
      atomicAdd(&ssum[ni * 16 + lr], ps[ni]);
      atomicAdd(&ssq[ni * 16 + lr], pq[ni]);
    }
    __syncthreads();
    if (threadIdx.x < 64) {
      atomicAdd(&stats[threadIdx.x], ssum[threadIdx.x]);
      atomicAdd(&stats[64 + threadIdx.x], ssq[threadIdx.x]);
    }
  }
}

// ---------------------------------------------------------------------------
// BN + next-layer q, wave per node: lane o normalizes channel o (from bf16 y),
// writes bf16 xb; q[n][h] via 8 shfl_xor butterflies.
__global__ void __launch_bounds__(256)
k_bnq(const __hip_bfloat16* __restrict__ y, const float* __restrict__ stats,
      const float* __restrict__ g, const float* __restrict__ be,
      const float* __restrict__ U, __hip_bfloat16* __restrict__ xb,
      float* __restrict__ q) {
  const int lane = threadIdx.x & 63;
  const int n = (int)(((long)blockIdx.x * blockDim.x + threadIdx.x) >> 6);
  if (n >= NN) return;

  float m = stats[lane] * (1.0f / NN);
  float v = stats[64 + lane] * (1.0f / NN) - m * m;
  float yv = b2f(reinterpret_cast<const ushort*>(y)[(size_t)n * 64 + lane]);
  float r = fmaf(g[lane] * rsqrtf(v + 1e-5f), yv - m, be[lane]);
  xb[(size_t)n * 64 + lane] = __float2bfloat16(r);

  float qv[8];
#pragma unroll
  for (int h = 0; h < 8; ++h) {
    float p = r * U[h * 64 + lane];
#pragma unroll
    for (int off = 32; off; off >>= 1) p += __shfl_xor(p, off, 64);
    qv[h] = p;
  }
  if (lane == 0) {
    float4* q4 = reinterpret_cast<float4*>(q + (size_t)n * 8);
    q4[0] = make_float4(qv[0] * L2E, qv[1] * L2E, qv[2] * L2E, qv[3] * L2E);
    q4[1] = make_float4(qv[4] * L2E, qv[5] * L2E, qv[6] * L2E, qv[7] * L2E);
  }
}

// ---------------------------------------------------------------------------
extern "C" void kernel_launch(void* const* d_in, const int* in_sizes, int n_in,
                              void* d_out, int out_size, void* d_ws, size_t ws_size,
                              hipStream_t stream) {
  const float* x   = (const float*)d_in[0];
  const int*   src = (const int*)d_in[1];
  const int*   dst = src + NE;
  const float* W1 = (const float*)d_in[2];
  const float* U1 = (const float*)d_in[3];
  const float* c1 = (const float*)d_in[4];
  const float* b1 = (const float*)d_in[5];
  const float* g1 = (const float*)d_in[6];
  const float* be1 = (const float*)d_in[7];
  const float* W2 = (const float*)d_in[8];
  const float* U2 = (const float*)d_in[9];
  const float* c2 = (const float*)d_in[10];
  const float* b2 = (const float*)d_in[11];
  const float* g2 = (const float*)d_in[12];
  const float* be2 = (const float*)d_in[13];
  const float* W3 = (const float*)d_in[14];
  const float* U3 = (const float*)d_in[15];
  const float* c3 = (const float*)d_in[16];
  const float* b3 = (const float*)d_in[17];
  float* out = (float*)d_out;

  // workspace layout (all sections 16B-aligned)
  float* ws   = (float*)d_ws;
  float* inv  = ws;                           // N
  float* q    = inv + NN;                     // N*8
  float* stats = q + (size_t)NN * 8;          // 256 (two layers' stats)
  uint4* a    = (uint4*)(stats + 256);        // NE (f16x8 attn weights)
  __hip_bfloat16* yb = (__hip_bfloat16*)(a + NE);        // N*64 bf16 (relu out)
  __hip_bfloat16* xb = yb + (size_t)NN * 64;             // N*64 bf16
  __hip_bfloat16* zb = xb + (size_t)NN * 64;             // N*512 bf16
  __hip_bfloat16* Wt1 = zb + (size_t)NN * 512;           // 64*512 bf16
  __hip_bfloat16* Wt2 = Wt1 + 64 * 512;
  __hip_bfloat16* Wt3 = Wt2 + 64 * 512;
  int* degin   = (int*)(Wt3 + 32 * 512);            // N
  int* cscbase = degin + NN;                        // N
  int* cursor  = cscbase + NN;                      // N (CSC end after scatter)
  int* bsum    = cursor + NN;                       // 256
  int* csrc    = bsum + 256;                        // NE
  int* dstpos  = csrc + NE;                         // NE
  float* stats1 = stats;
  float* stats2 = stats + 128;

  const int BLK = 256;
  dim3 b256(BLK);

  // ---- CSC build (once; reused by all 3 layers) ----
  hipMemsetAsync(degin, 0, (size_t)NN * 4, stream);
  hipMemsetAsync(stats, 0, 256 * 4, stream);
  k_deg<<<dim3((NE + BLK - 1) / BLK), b256, 0, stream>>>(dst, degin);
  k_scan1<<<dim3(SGRID), dim3(SBLK), 0, stream>>>(degin, bsum);
  k_scan2<<<dim3(1), dim3(256), 0, stream>>>(bsum);
  k_scan3<<<dim3(SGRID), dim3(SBLK), 0, stream>>>(degin, bsum, cscbase, cursor);
  k_scatter<<<dim3(8 * 104), b256, 0, stream>>>(src, dst, cursor, csrc);
  k_dstpos<<<dim3(NN * 64 / BLK), b256, 0, stream>>>(cscbase, degin, dstpos, inv);

  const int qgrid = (NN + BLK - 1) / BLK;
  const int attn_grid = (NE + BLK - 1) / BLK;
  const int node_grid = NN * 64 / BLK;             // 12500 (wave per node)
  const int zgemm_grid = (NN + 255) / 256;         // 196
  const int wtgrid = (64 * 512 * 2 + 32 * 512 + BLK - 1) / BLK;

  k_wt<<<dim3(wtgrid), b256, 0, stream>>>(W1, W2, W3, Wt1, Wt2, Wt3);
  k_qx<<<dim3(qgrid), b256, 0, stream>>>(x, U1, q, xb);

  // ---- layer 1 ----
  k_attn<<<dim3(attn_grid), b256, 0, stream>>>(csrc, dstpos, q, c1, inv, a);
  k_zagg<<<dim3(node_grid), b256, 0, stream>>>(cscbase, cursor, csrc, a,
                                               (const ushort*)xb, inv, c1, zb);
  k_zgemm_ep<64, true><<<dim3(zgemm_grid), b256, 0, stream>>>(zb, Wt1, b1, yb, nullptr, stats1);
  k_bnq<<<dim3(node_grid), b256, 0, stream>>>(yb, stats1, g1, be1, U2, xb, q);

  // ---- layer 2 ----
  k_attn<<<dim3(attn_grid), b256, 0, stream>>>(csrc, dstpos, q, c2, inv, a);
  k_zagg<<<dim3(node_grid), b256, 0, stream>>>(cscbase, cursor, csrc, a,
                                               (const ushort*)xb, inv, c2, zb);
  k_zgemm_ep<64, true><<<dim3(zgemm_grid), b256, 0, stream>>>(zb, Wt2, b2, yb, nullptr, stats2);
  k_bnq<<<dim3(node_grid), b256, 0, stream>>>(yb, stats2, g2, be2, U3, xb, q);

  // ---- layer 3 ----
  k_attn<<<dim3(attn_grid), b256, 0, stream>>>(csrc, dstpos, q, c3, inv, a);
  k_zagg<<<dim3(node_grid), b256, 0, stream>>>(cscbase, cursor, csrc, a,
                                               (const ushort*)xb, inv, c3, zb);
  k_zgemm_ep<32, false><<<dim3(zgemm_grid), b256, 0, stream>>>(zb, Wt3, b3, nullptr, out, nullptr);
}